// Round 4
// baseline (340.333 us; speedup 1.0000x reference)
//
#include <hip/hip_runtime.h>
#include <math.h>

#define Bb 4
#define Nn 384
#define CSs 384
#define Hh 12
#define Cc 16
#define PQq 4
#define PVv 8
#define FPROJ 1152
#define FCAT 576
#define INFV 100000.0f
#define EPSV 1e-8f
#define JT 128

// ws layout (floats)
#define WS_PROJ 0
#define WS_KP   (1536*1152)             // 1,769,472
#define WS_VP   (WS_KP + 48*384*16)     // 2,064,384
#define WS_KPP  (WS_VP + 48*384*16)     // 2,359,296
#define WS_VPP  (WS_KPP + 48*384*12)    // 2,580,480
#define WS_CAT  (WS_VPP + 48*384*24)    // 3,022,848

// ---------------- Kernel 1: fused projection GEMM ----------------
// grid 384 = 3 col-thirds x 128 row-tiles(12 rows); 384 threads, 1 col/thread
__global__ __launch_bounds__(384) void proj_kernel(
    const float* __restrict__ s,
    const float* __restrict__ w_q, const float* __restrict__ b_q,
    const float* __restrict__ w_kv, const float* __restrict__ b_kv,
    const float* __restrict__ w_qp, const float* __restrict__ b_qp,
    const float* __restrict__ w_kvp, const float* __restrict__ b_kvp,
    float* __restrict__ proj)
{
    const int third = blockIdx.x / 128;
    const int row0 = (blockIdx.x % 128) * 12;
    const int t = threadIdx.x;
    const int f = third * 384 + t;

    const float* wp; int ld; float bi;
    if (f < 192)      { wp = w_q + f;         ld = 192; bi = b_q[f]; }
    else if (f < 576) { wp = w_kv + (f-192);  ld = 384; bi = b_kv[f-192]; }
    else if (f < 720) { wp = w_qp + (f-576);  ld = 144; bi = b_qp[f-576]; }
    else              { wp = w_kvp + (f-720); ld = 432; bi = b_kvp[f-720]; }

    float acc[12];
#pragma unroll
    for (int r = 0; r < 12; ++r) acc[r] = 0.0f;

    const float* s0 = s + (size_t)row0 * CSs;

    for (int d = 0; d < CSs; d += 4) {
        float4 sv[12];
#pragma unroll
        for (int r = 0; r < 12; ++r)
            sv[r] = *(const float4*)(s0 + (size_t)r * CSs + d);   // uniform addr
#pragma unroll
        for (int dd = 0; dd < 4; ++dd) {
            float wv = *wp; wp += ld;
#pragma unroll
            for (int r = 0; r < 12; ++r)
                acc[r] += ((const float*)&sv[r])[dd] * wv;
        }
    }
#pragma unroll
    for (int r = 0; r < 12; ++r)
        proj[(size_t)(row0 + r) * FPROJ + f] = acc[r] + bi;
}

// ---------------- Kernel 2: rigid-apply + pack ----------------
__global__ __launch_bounds__(192) void pack_kernel(
    const float* __restrict__ proj,
    const float* __restrict__ rot, const float* __restrict__ trans,
    float* __restrict__ Kp, float* __restrict__ Vp,
    float* __restrict__ KPp, float* __restrict__ VPp)
{
    const int bn = blockIdx.x;
    const int b = bn / Nn;
    const int n = bn % Nn;
    const int t = threadIdx.x;
    const float* R = rot + (size_t)bn * 9;
    const float* T = trans + (size_t)bn * 3;
    const float* pr = proj + (size_t)bn * FPROJ;

    if (t < 144) {
        float x = pr[720 + t];
        float y = pr[720 + 144 + t];
        float z = pr[720 + 288 + t];
        float ox = R[0]*x + R[1]*y + R[2]*z + T[0];
        float oy = R[3]*x + R[4]*y + R[5]*z + T[1];
        float oz = R[6]*x + R[7]*y + R[8]*z + T[2];
        int h = t / 12, pp = t % 12;
        int bh = b * Hh + h;
        if (pp < PQq) {
            float* o = KPp + ((size_t)(bh * Nn + n)) * 12 + pp * 3;
            o[0] = ox; o[1] = oy; o[2] = oz;
        } else {
            float* o = VPp + ((size_t)(bh * Nn + n)) * 24 + (pp - PQq) * 3;
            o[0] = ox; o[1] = oy; o[2] = oz;
        }
    }
#pragma unroll
    for (int rep = 0; rep < 2; ++rep) {
        int idx = t + rep * 192;
        int h = idx / 32, c2 = idx % 32;
        int bh = b * Hh + h;
        float v = pr[192 + h * 32 + c2];
        if (c2 < 16) Kp[((size_t)(bh * Nn + n)) * 16 + c2] = v;
        else         Vp[((size_t)(bh * Nn + n)) * 16 + (c2 - 16)] = v;
    }
}

// ---------------- Kernel 3: attention v4 ----------------
// grid = B*H*48 = 2304 blocks, 256 threads (4 waves); 8 rows/block,
// wave w handles rows {i0+2w, i0+2w+1}; lane = j (64 distinct j per read).
__global__ __launch_bounds__(256) void attn_kernel(
    const float* __restrict__ proj,
    const float* __restrict__ Kp, const float* __restrict__ Vp,
    const float* __restrict__ KPp, const float* __restrict__ VPp,
    const float* __restrict__ rot, const float* __restrict__ trans,
    const float* __restrict__ mask, const float* __restrict__ head_weights,
    float* __restrict__ cat)
{
    __shared__ float4 stK[4*JT];    // 8 KB   [c4][j]
    __shared__ float4 stKP[3*JT];   // 6 KB
    __shared__ float4 stV[4*JT];    // 8 KB
    __shared__ float4 stVP[6*JT];   // 12 KB
    __shared__ float  stM[Nn];      // 1.5 KB

    const int bid = blockIdx.x;
    const int ib = bid % 48;
    const int h  = (bid / 48) % Hh;
    const int b  = bid / (48 * Hh);
    const int tid = threadIdx.x;
    const int w = tid >> 6;
    const int lane = tid & 63;
    const int i0r = b * Nn + ib * 8 + 2 * w;   // row0 global index
    const int bh = b * Hh + h;

    for (int e = tid; e < Nn; e += 256) stM[e] = mask[b * Nn + e];

    // q rows (wave-uniform addresses)
    float qv0[16], qv1[16];
    {
        const float* qrow = proj + (size_t)i0r * FPROJ + h * Cc;
#pragma unroll
        for (int c = 0; c < 16; ++c) { qv0[c] = qrow[c]; qv1[c] = qrow[FPROJ + c]; }
    }

    // q_pts rigid-apply for both rows
    float qp0[12], qp1[12];
    {
        const float* R0 = rot + (size_t)i0r * 9;
        const float* T0 = trans + (size_t)i0r * 3;
        const float* pq0 = proj + (size_t)i0r * FPROJ + 576;
#pragma unroll
        for (int p = 0; p < PQq; ++p) {
            float x = pq0[h * PQq + p];
            float y = pq0[48 + h * PQq + p];
            float z = pq0[96 + h * PQq + p];
            qp0[p*3+0] = R0[0]*x + R0[1]*y + R0[2]*z + T0[0];
            qp0[p*3+1] = R0[3]*x + R0[4]*y + R0[5]*z + T0[1];
            qp0[p*3+2] = R0[6]*x + R0[7]*y + R0[8]*z + T0[2];
        }
        const float* R1 = R0 + 9;
        const float* T1 = T0 + 3;
        const float* pq1 = pq0 + FPROJ;
#pragma unroll
        for (int p = 0; p < PQq; ++p) {
            float x = pq1[h * PQq + p];
            float y = pq1[48 + h * PQq + p];
            float z = pq1[96 + h * PQq + p];
            qp1[p*3+0] = R1[0]*x + R1[1]*y + R1[2]*z + T1[0];
            qp1[p*3+1] = R1[3]*x + R1[4]*y + R1[5]*z + T1[1];
            qp1[p*3+2] = R1[6]*x + R1[7]*y + R1[8]*z + T1[2];
        }
    }

    const float hw = log1pf(expf(head_weights[h]));
    const float wc = -0.5f * hw * 0.13608276348795434f;   // * sqrt(1/54)
    const float scale2 = 2.0f * 0.14433756729740643f;     // 2 * sqrt(1/48)
    const float mi0 = mask[i0r];
    const float mi1 = mask[i0r + 1];

    const float* KpB  = Kp  + (size_t)(bh * Nn) * 16;
    const float* VpB  = Vp  + (size_t)(bh * Nn) * 16;
    const float* KPpB = KPp + (size_t)(bh * Nn) * 12;
    const float* VPpB = VPp + (size_t)(bh * Nn) * 24;

    float m0 = -3.0e38f, m1 = -3.0e38f, ssum0 = 0.0f, ssum1 = 0.0f;
    float acc0[16], acc1[16], accp0[24], accp1[24];
#pragma unroll
    for (int c = 0; c < 16; ++c) { acc0[c] = 0.0f; acc1[c] = 0.0f; }
#pragma unroll
    for (int tt = 0; tt < 24; ++tt) { accp0[tt] = 0.0f; accp1[tt] = 0.0f; }

#define LOGIT_ROW(qq, qpp, mii) (scale2*( \
     qq[0]*k0.x+qq[1]*k0.y+qq[2]*k0.z+qq[3]*k0.w \
    +qq[4]*k1.x+qq[5]*k1.y+qq[6]*k1.z+qq[7]*k1.w \
    +qq[8]*k2.x+qq[9]*k2.y+qq[10]*k2.z+qq[11]*k2.w \
    +qq[12]*k3.x+qq[13]*k3.y+qq[14]*k3.z+qq[15]*k3.w) \
    + wc*( (qpp[0]-p0.x)*(qpp[0]-p0.x)+(qpp[1]-p0.y)*(qpp[1]-p0.y) \
          +(qpp[2]-p0.z)*(qpp[2]-p0.z)+(qpp[3]-p0.w)*(qpp[3]-p0.w) \
          +(qpp[4]-p1.x)*(qpp[4]-p1.x)+(qpp[5]-p1.y)*(qpp[5]-p1.y) \
          +(qpp[6]-p1.z)*(qpp[6]-p1.z)+(qpp[7]-p1.w)*(qpp[7]-p1.w) \
          +(qpp[8]-p2.x)*(qpp[8]-p2.x)+(qpp[9]-p2.y)*(qpp[9]-p2.y) \
          +(qpp[10]-p2.z)*(qpp[10]-p2.z)+(qpp[11]-p2.w)*(qpp[11]-p2.w)) \
    + INFV*(mii*mj - 1.0f))

#define ACC_ROW(aa, accA, accpA) do { \
    accA[0]+=aa*v0.x; accA[1]+=aa*v0.y; accA[2]+=aa*v0.z; accA[3]+=aa*v0.w; \
    accA[4]+=aa*v1.x; accA[5]+=aa*v1.y; accA[6]+=aa*v1.z; accA[7]+=aa*v1.w; \
    accA[8]+=aa*v2.x; accA[9]+=aa*v2.y; accA[10]+=aa*v2.z; accA[11]+=aa*v2.w; \
    accA[12]+=aa*v3.x; accA[13]+=aa*v3.y; accA[14]+=aa*v3.z; accA[15]+=aa*v3.w; \
    accpA[0]+=aa*q0.x; accpA[1]+=aa*q0.y; accpA[2]+=aa*q0.z; accpA[3]+=aa*q0.w; \
    accpA[4]+=aa*q1.x; accpA[5]+=aa*q1.y; accpA[6]+=aa*q1.z; accpA[7]+=aa*q1.w; \
    accpA[8]+=aa*q2.x; accpA[9]+=aa*q2.y; accpA[10]+=aa*q2.z; accpA[11]+=aa*q2.w; \
    accpA[12]+=aa*q3.x; accpA[13]+=aa*q3.y; accpA[14]+=aa*q3.z; accpA[15]+=aa*q3.w; \
    accpA[16]+=aa*q4.x; accpA[17]+=aa*q4.y; accpA[18]+=aa*q4.z; accpA[19]+=aa*q4.w; \
    accpA[20]+=aa*q5.x; accpA[21]+=aa*q5.y; accpA[22]+=aa*q5.z; accpA[23]+=aa*q5.w; \
} while (0)

    for (int tile = 0; tile < Nn / JT; ++tile) {
        const int jb = tile * JT;
        // ---- stage (transposed [c4][j] layout) ----
#pragma unroll
        for (int k = 0; k < 2; ++k) {
            int e = tid + k * 256;
            int j = e >> 2, c4 = e & 3;
            stK[c4 * JT + j] = *(const float4*)(KpB + ((size_t)(jb + j)) * 16 + c4 * 4);
            stV[c4 * JT + j] = *(const float4*)(VpB + ((size_t)(jb + j)) * 16 + c4 * 4);
        }
        {
            int cp = tid >> 7, j = tid & 127;
            stKP[cp * JT + j] = *(const float4*)(KPpB + ((size_t)(jb + j)) * 12 + cp * 4);
        }
        if (tid < 128) {
            stKP[2 * JT + tid] = *(const float4*)(KPpB + ((size_t)(jb + tid)) * 12 + 8);
        }
#pragma unroll
        for (int k = 0; k < 3; ++k) {
            int e = tid + k * 256;
            int cp = e >> 7, j = e & 127;
            stVP[cp * JT + j] = *(const float4*)(VPpB + ((size_t)(jb + j)) * 24 + cp * 4);
        }
        __syncthreads();

        // ---- phase A: logits for 2 j (one per 64-lane sweep) x 2 rows ----
        float l00, l01, l10, l11;
        float tmax0, tmax1;
        {
            int j = lane;
            float4 k0 = stK[j], k1 = stK[JT + j], k2 = stK[2*JT + j], k3 = stK[3*JT + j];
            float4 p0 = stKP[j], p1 = stKP[JT + j], p2 = stKP[2*JT + j];
            float mj = stM[jb + j];
            l00 = LOGIT_ROW(qv0, qp0, mi0);
            l01 = LOGIT_ROW(qv1, qp1, mi1);
        }
        {
            int j = 64 + lane;
            float4 k0 = stK[j], k1 = stK[JT + j], k2 = stK[2*JT + j], k3 = stK[3*JT + j];
            float4 p0 = stKP[j], p1 = stKP[JT + j], p2 = stKP[2*JT + j];
            float mj = stM[jb + j];
            l10 = LOGIT_ROW(qv0, qp0, mi0);
            l11 = LOGIT_ROW(qv1, qp1, mi1);
        }
        tmax0 = fmaxf(l00, l10);
        tmax1 = fmaxf(l01, l11);

        // ---- rescale (skip when no lane's max grew) ----
        if (__any((tmax0 > m0) || (tmax1 > m1))) {
            float mn0 = fmaxf(m0, tmax0);
            float mn1 = fmaxf(m1, tmax1);
            float f0 = __expf(m0 - mn0);
            float f1 = __expf(m1 - mn1);
            m0 = mn0; m1 = mn1;
            ssum0 *= f0; ssum1 *= f1;
#pragma unroll
            for (int c = 0; c < 16; ++c) { acc0[c] *= f0; acc1[c] *= f1; }
#pragma unroll
            for (int tt = 0; tt < 24; ++tt) { accp0[tt] *= f0; accp1[tt] *= f1; }
        }

        // ---- phase B: accumulate ----
        {
            int j = lane;
            float4 v0 = stV[j], v1 = stV[JT + j], v2 = stV[2*JT + j], v3 = stV[3*JT + j];
            float4 q0 = stVP[j], q1 = stVP[JT + j], q2 = stVP[2*JT + j];
            float4 q3 = stVP[3*JT + j], q4 = stVP[4*JT + j], q5 = stVP[5*JT + j];
            float a0 = __expf(l00 - m0); ssum0 += a0;
            float a1 = __expf(l01 - m1); ssum1 += a1;
            ACC_ROW(a0, acc0, accp0);
            ACC_ROW(a1, acc1, accp1);
        }
        {
            int j = 64 + lane;
            float4 v0 = stV[j], v1 = stV[JT + j], v2 = stV[2*JT + j], v3 = stV[3*JT + j];
            float4 q0 = stVP[j], q1 = stVP[JT + j], q2 = stVP[2*JT + j];
            float4 q3 = stVP[3*JT + j], q4 = stVP[4*JT + j], q5 = stVP[5*JT + j];
            float a0 = __expf(l10 - m0); ssum0 += a0;
            float a1 = __expf(l11 - m1); ssum1 += a1;
            ACC_ROW(a0, acc0, accp0);
            ACC_ROW(a1, acc1, accp1);
        }
        __syncthreads();
    }

    // ---- 64-lane butterfly merge ----
    float M0 = m0, M1 = m1;
#pragma unroll
    for (int off = 32; off >= 1; off >>= 1) {
        M0 = fmaxf(M0, __shfl_xor(M0, off));
        M1 = fmaxf(M1, __shfl_xor(M1, off));
    }
    {
        float f0 = __expf(m0 - M0);
        float f1 = __expf(m1 - M1);
        ssum0 *= f0; ssum1 *= f1;
#pragma unroll
        for (int c = 0; c < 16; ++c) { acc0[c] *= f0; acc1[c] *= f1; }
#pragma unroll
        for (int tt = 0; tt < 24; ++tt) { accp0[tt] *= f0; accp1[tt] *= f1; }
    }
#pragma unroll
    for (int off = 32; off >= 1; off >>= 1) {
        ssum0 += __shfl_xor(ssum0, off);
        ssum1 += __shfl_xor(ssum1, off);
#pragma unroll
        for (int c = 0; c < 16; ++c) {
            acc0[c] += __shfl_xor(acc0[c], off);
            acc1[c] += __shfl_xor(acc1[c], off);
        }
#pragma unroll
        for (int tt = 0; tt < 24; ++tt) {
            accp0[tt] += __shfl_xor(accp0[tt], off);
            accp1[tt] += __shfl_xor(accp1[tt], off);
        }
    }

    // ---- epilogue (STATIC indexing only) ----
    const float inv0 = 1.0f / ssum0;
    const float inv1 = 1.0f / ssum1;
    float* crow0 = cat + (size_t)i0r * FCAT;
    float* crow1 = crow0 + FCAT;

#pragma unroll
    for (int c = 0; c < 16; ++c) {
        if (lane == c)           crow0[h * 16 + c] = acc0[c] * inv0;
        else if (lane == 16 + c) crow1[h * 16 + c] = acc1[c] * inv1;
    }
#pragma unroll
    for (int p = 0; p < 8; ++p) {
        if (lane == 32 + p) {
            const float* R = rot + (size_t)i0r * 9;
            const float* T = trans + (size_t)i0r * 3;
            float g0 = accp0[p*3+0] * inv0 - T[0];
            float g1 = accp0[p*3+1] * inv0 - T[1];
            float g2 = accp0[p*3+2] * inv0 - T[2];
            float lx = R[0]*g0 + R[3]*g1 + R[6]*g2;
            float ly = R[1]*g0 + R[4]*g1 + R[7]*g2;
            float lz = R[2]*g0 + R[5]*g1 + R[8]*g2;
            crow0[192 + h*8 + p] = lx;
            crow0[288 + h*8 + p] = ly;
            crow0[384 + h*8 + p] = lz;
            crow0[480 + h*8 + p] = sqrtf(lx*lx + ly*ly + lz*lz + EPSV);
        } else if (lane == 40 + p) {
            const float* R = rot + (size_t)(i0r + 1) * 9;
            const float* T = trans + (size_t)(i0r + 1) * 3;
            float g0 = accp1[p*3+0] * inv1 - T[0];
            float g1 = accp1[p*3+1] * inv1 - T[1];
            float g2 = accp1[p*3+2] * inv1 - T[2];
            float lx = R[0]*g0 + R[3]*g1 + R[6]*g2;
            float ly = R[1]*g0 + R[4]*g1 + R[7]*g2;
            float lz = R[2]*g0 + R[5]*g1 + R[8]*g2;
            crow1[192 + h*8 + p] = lx;
            crow1[288 + h*8 + p] = ly;
            crow1[384 + h*8 + p] = lz;
            crow1[480 + h*8 + p] = sqrtf(lx*lx + ly*ly + lz*lz + EPSV);
        }
    }
#undef LOGIT_ROW
#undef ACC_ROW
}

// ---------------- Kernel 4: output GEMM ----------------
__global__ __launch_bounds__(384) void out_kernel(
    const float* __restrict__ cat,
    const float* __restrict__ w_out, const float* __restrict__ b_out,
    float* __restrict__ out)
{
    const int row0 = blockIdx.x * 6;
    const int t = threadIdx.x;
    float acc[6] = {0,0,0,0,0,0};
    const float* wp = w_out + t;
    const float* c0 = cat + (size_t)row0 * FCAT;
    for (int d = 0; d < FCAT; d += 4) {
        float4 cv[6];
#pragma unroll
        for (int r = 0; r < 6; ++r)
            cv[r] = *(const float4*)(c0 + (size_t)r * FCAT + d);   // uniform addr
#pragma unroll
        for (int dd = 0; dd < 4; ++dd) {
            float wv = wp[(size_t)(d + dd) * 384];
#pragma unroll
            for (int r = 0; r < 6; ++r) acc[r] += ((const float*)&cv[r])[dd] * wv;
        }
    }
    const float bb = b_out[t];
#pragma unroll
    for (int r = 0; r < 6; ++r) out[(size_t)(row0 + r) * 384 + t] = acc[r] + bb;
}

extern "C" void kernel_launch(void* const* d_in, const int* in_sizes, int n_in,
                              void* d_out, int out_size, void* d_ws, size_t ws_size,
                              hipStream_t stream) {
    const float* s     = (const float*)d_in[0];
    const float* rot   = (const float*)d_in[2];
    const float* trans = (const float*)d_in[3];
    const float* mask  = (const float*)d_in[4];
    const float* w_q   = (const float*)d_in[5];
    const float* b_q   = (const float*)d_in[6];
    const float* w_kv  = (const float*)d_in[7];
    const float* b_kv  = (const float*)d_in[8];
    const float* w_qp  = (const float*)d_in[13];
    const float* b_qp  = (const float*)d_in[14];
    const float* w_kvp = (const float*)d_in[15];
    const float* b_kvp = (const float*)d_in[16];
    const float* hwts  = (const float*)d_in[17];
    const float* w_out = (const float*)d_in[18];
    const float* b_out = (const float*)d_in[19];

    float* ws    = (float*)d_ws;
    float* proj  = ws + WS_PROJ;
    float* Kp    = ws + WS_KP;
    float* Vp    = ws + WS_VP;
    float* KPp   = ws + WS_KPP;
    float* VPp   = ws + WS_VPP;
    float* catb  = ws + WS_CAT;
    float* out   = (float*)d_out;

    hipLaunchKernelGGL(proj_kernel, dim3(384), dim3(384), 0, stream,
                       s, w_q, b_q, w_kv, b_kv, w_qp, b_qp, w_kvp, b_kvp, proj);
    hipLaunchKernelGGL(pack_kernel, dim3(1536), dim3(192), 0, stream,
                       proj, rot, trans, Kp, Vp, KPp, VPp);
    hipLaunchKernelGGL(attn_kernel, dim3(2304), dim3(256), 0, stream,
                       proj, Kp, Vp, KPp, VPp, rot, trans, mask, hwts, catb);
    hipLaunchKernelGGL(out_kernel, dim3(256), dim3(384), 0, stream,
                       catb, w_out, b_out, out);
}

// Round 5
// 150.252 us; speedup vs baseline: 2.2651x; 2.2651x over previous
//
#include <hip/hip_runtime.h>
#include <math.h>

#define Bb 4
#define Nn 384
#define CSs 384
#define Hh 12
#define Cc 16
#define PQq 4
#define PVv 8
#define FPROJ 1152
#define FCAT 576
#define INFV 100000.0f
#define EPSV 1e-8f
#define JT 128

// ws layout (floats)
#define WS_PROJ 0
#define WS_KP   (1536*1152)             // 1,769,472
#define WS_VP   (WS_KP + 48*384*16)     // 2,064,384
#define WS_KPP  (WS_VP + 48*384*16)     // 2,359,296
#define WS_VPP  (WS_KPP + 48*384*12)    // 2,580,480
#define WS_CAT  (WS_VPP + 48*384*24)    // 3,022,848

// ---------------- Kernel 1: fused projection GEMM ----------------
// grid 384 = 3 col-thirds x 128 row-tiles(12 rows); 384 threads, 1 col/thread
__global__ __launch_bounds__(384) void proj_kernel(
    const float* __restrict__ s,
    const float* __restrict__ w_q, const float* __restrict__ b_q,
    const float* __restrict__ w_kv, const float* __restrict__ b_kv,
    const float* __restrict__ w_qp, const float* __restrict__ b_qp,
    const float* __restrict__ w_kvp, const float* __restrict__ b_kvp,
    float* __restrict__ proj)
{
    const int third = blockIdx.x / 128;
    const int row0 = (blockIdx.x % 128) * 12;
    const int t = threadIdx.x;
    const int f = third * 384 + t;

    const float* wp; int ld; float bi;
    if (f < 192)      { wp = w_q + f;         ld = 192; bi = b_q[f]; }
    else if (f < 576) { wp = w_kv + (f-192);  ld = 384; bi = b_kv[f-192]; }
    else if (f < 720) { wp = w_qp + (f-576);  ld = 144; bi = b_qp[f-576]; }
    else              { wp = w_kvp + (f-720); ld = 432; bi = b_kvp[f-720]; }

    float acc[12];
#pragma unroll
    for (int r = 0; r < 12; ++r) acc[r] = 0.0f;

    const float* s0 = s + (size_t)row0 * CSs;

    for (int d = 0; d < CSs; d += 4) {
        float4 sv[12];
#pragma unroll
        for (int r = 0; r < 12; ++r)
            sv[r] = *(const float4*)(s0 + (size_t)r * CSs + d);   // uniform addr
#pragma unroll
        for (int dd = 0; dd < 4; ++dd) {
            float wv = *wp; wp += ld;
#pragma unroll
            for (int r = 0; r < 12; ++r)
                acc[r] += ((const float*)&sv[r])[dd] * wv;
        }
    }
#pragma unroll
    for (int r = 0; r < 12; ++r)
        proj[(size_t)(row0 + r) * FPROJ + f] = acc[r] + bi;
}

// ---------------- Kernel 2: rigid-apply + pack ----------------
__global__ __launch_bounds__(192) void pack_kernel(
    const float* __restrict__ proj,
    const float* __restrict__ rot, const float* __restrict__ trans,
    float* __restrict__ Kp, float* __restrict__ Vp,
    float* __restrict__ KPp, float* __restrict__ VPp)
{
    const int bn = blockIdx.x;
    const int b = bn / Nn;
    const int n = bn % Nn;
    const int t = threadIdx.x;
    const float* R = rot + (size_t)bn * 9;
    const float* T = trans + (size_t)bn * 3;
    const float* pr = proj + (size_t)bn * FPROJ;

    if (t < 144) {
        float x = pr[720 + t];
        float y = pr[720 + 144 + t];
        float z = pr[720 + 288 + t];
        float ox = R[0]*x + R[1]*y + R[2]*z + T[0];
        float oy = R[3]*x + R[4]*y + R[5]*z + T[1];
        float oz = R[6]*x + R[7]*y + R[8]*z + T[2];
        int h = t / 12, pp = t % 12;
        int bh = b * Hh + h;
        if (pp < PQq) {
            float* o = KPp + ((size_t)(bh * Nn + n)) * 12 + pp * 3;
            o[0] = ox; o[1] = oy; o[2] = oz;
        } else {
            float* o = VPp + ((size_t)(bh * Nn + n)) * 24 + (pp - PQq) * 3;
            o[0] = ox; o[1] = oy; o[2] = oz;
        }
    }
#pragma unroll
    for (int rep = 0; rep < 2; ++rep) {
        int idx = t + rep * 192;
        int h = idx / 32, c2 = idx % 32;
        int bh = b * Hh + h;
        float v = pr[192 + h * 32 + c2];
        if (c2 < 16) Kp[((size_t)(bh * Nn + n)) * 16 + c2] = v;
        else         Vp[((size_t)(bh * Nn + n)) * 16 + (c2 - 16)] = v;
    }
}

// ---------------- Kernel 3: attention v5 ----------------
// grid = B*H*24 = 1152 blocks, 256 threads (4 waves); 16 rows/block.
// Wave = 4 row-groups x 16 j-lanes; the 4 groups read IDENTICAL LDS addresses
// (same-address broadcast = free); each lane keeps ONE row's 41 accumulators
// in registers; epilogue is fully static-indexed (rule #20).
__global__ __launch_bounds__(256, 3) void attn_kernel(
    const float* __restrict__ proj,
    const float* __restrict__ Kp, const float* __restrict__ Vp,
    const float* __restrict__ KPp, const float* __restrict__ VPp,
    const float* __restrict__ rot, const float* __restrict__ trans,
    const float* __restrict__ mask, const float* __restrict__ head_weights,
    float* __restrict__ cat)
{
    __shared__ float4 stK[4*JT];    // 8 KB   [c4][j]
    __shared__ float4 stKP[3*JT];   // 6 KB
    __shared__ float4 stV[4*JT];    // 8 KB
    __shared__ float4 stVP[6*JT];   // 12 KB
    __shared__ float  stM[Nn];      // 1.5 KB

    const int bid = blockIdx.x;
    const int ib = bid % 24;
    const int h  = (bid / 24) % Hh;
    const int b  = bid / (24 * Hh);
    const int tid = threadIdx.x;
    const int w = tid >> 6;
    const int lane = tid & 63;
    const int rg = lane >> 4;       // row-group 0..3
    const int jl = lane & 15;       // j-lane 0..15
    const int i = ib * 16 + w * 4 + rg;
    const int bnI = b * Nn + i;
    const int bh = b * Hh + h;

    for (int e = tid; e < Nn; e += 256) stM[e] = mask[b * Nn + e];

    // q row
    const float* qrow = proj + (size_t)bnI * FPROJ + h * Cc;
    float qv[16];
#pragma unroll
    for (int c = 0; c < 16; ++c) qv[c] = qrow[c];

    // q_pts rigid-apply
    const float* R = rot + (size_t)bnI * 9;
    const float* T = trans + (size_t)bnI * 3;
    float qpv[12];
    {
        const float* pq = proj + (size_t)bnI * FPROJ + 576;
#pragma unroll
        for (int p = 0; p < PQq; ++p) {
            float x = pq[h * PQq + p];
            float y = pq[48 + h * PQq + p];
            float z = pq[96 + h * PQq + p];
            qpv[p*3+0] = R[0]*x + R[1]*y + R[2]*z + T[0];
            qpv[p*3+1] = R[3]*x + R[4]*y + R[5]*z + T[1];
            qpv[p*3+2] = R[6]*x + R[7]*y + R[8]*z + T[2];
        }
    }

    const float hw = log1pf(expf(head_weights[h]));
    const float wc = -0.5f * hw * 0.13608276348795434f;   // * sqrt(1/54)
    const float scale2 = 2.0f * 0.14433756729740643f;     // 2 * sqrt(1/48)
    const float mi = mask[bnI];

    const float* KpB  = Kp  + (size_t)(bh * Nn) * 16;
    const float* VpB  = Vp  + (size_t)(bh * Nn) * 16;
    const float* KPpB = KPp + (size_t)(bh * Nn) * 12;
    const float* VPpB = VPp + (size_t)(bh * Nn) * 24;

    float m = -3.0e38f, ssum = 0.0f;
    float acc[16]; float accp[24];
#pragma unroll
    for (int c = 0; c < 16; ++c) acc[c] = 0.0f;
#pragma unroll
    for (int tt = 0; tt < 24; ++tt) accp[tt] = 0.0f;

    for (int tile = 0; tile < Nn / JT; ++tile) {
        const int jb = tile * JT;
        // ---- stage (transposed [c4][j] layout), coalesced float4 ----
#pragma unroll
        for (int k = 0; k < 2; ++k) {
            int e = tid + k * 256;
            int j = e >> 2, c4 = e & 3;
            stK[c4 * JT + j] = *(const float4*)(KpB + ((size_t)(jb + j)) * 16 + c4 * 4);
            stV[c4 * JT + j] = *(const float4*)(VpB + ((size_t)(jb + j)) * 16 + c4 * 4);
        }
        {
            int cp = tid >> 7, j = tid & 127;
            stKP[cp * JT + j] = *(const float4*)(KPpB + ((size_t)(jb + j)) * 12 + cp * 4);
        }
        if (tid < 128) {
            stKP[2 * JT + tid] = *(const float4*)(KPpB + ((size_t)(jb + tid)) * 12 + 8);
        }
#pragma unroll
        for (int k = 0; k < 3; ++k) {
            int e = tid + k * 256;
            int cp = e >> 7, j = e & 127;
            stVP[cp * JT + j] = *(const float4*)(VPpB + ((size_t)(jb + j)) * 24 + cp * 4);
        }
        __syncthreads();

        // ---- phase A: logits (8 j per lane, 4-way broadcast across groups) ----
        float lgv[8];
        float tmax = -3.0e38f;
#pragma unroll
        for (int jj = 0; jj < 8; ++jj) {
            int j16 = jj * 16 + jl;
            float4 k0 = stK[j16], k1 = stK[JT + j16], k2 = stK[2*JT + j16], k3 = stK[3*JT + j16];
            float dot = qv[0]*k0.x + qv[1]*k0.y + qv[2]*k0.z + qv[3]*k0.w
                      + qv[4]*k1.x + qv[5]*k1.y + qv[6]*k1.z + qv[7]*k1.w
                      + qv[8]*k2.x + qv[9]*k2.y + qv[10]*k2.z + qv[11]*k2.w
                      + qv[12]*k3.x + qv[13]*k3.y + qv[14]*k3.z + qv[15]*k3.w;
            float4 p0 = stKP[j16], p1 = stKP[JT + j16], p2 = stKP[2*JT + j16];
            float d0 = qpv[0]-p0.x, d1 = qpv[1]-p0.y, d2 = qpv[2]-p0.z, d3 = qpv[3]-p0.w;
            float d4 = qpv[4]-p1.x, d5 = qpv[5]-p1.y, d6 = qpv[6]-p1.z, d7 = qpv[7]-p1.w;
            float d8 = qpv[8]-p2.x, d9 = qpv[9]-p2.y, d10 = qpv[10]-p2.z, d11 = qpv[11]-p2.w;
            float sq = d0*d0 + d1*d1 + d2*d2 + d3*d3 + d4*d4 + d5*d5
                     + d6*d6 + d7*d7 + d8*d8 + d9*d9 + d10*d10 + d11*d11;
            float lgt = scale2 * dot + wc * sq + INFV * (mi * stM[jb + j16] - 1.0f);
            lgv[jj] = lgt;
            tmax = fmaxf(tmax, lgt);
        }

        // ---- rescale (skip when no lane's max grew) ----
        if (__any(tmax > m)) {
            float mnew = fmaxf(m, tmax);
            float f = __expf(m - mnew);
            m = mnew;
            ssum *= f;
#pragma unroll
            for (int c = 0; c < 16; ++c) acc[c] *= f;
#pragma unroll
            for (int tt = 0; tt < 24; ++tt) accp[tt] *= f;
        }

        // ---- phase B: accumulate ----
#pragma unroll
        for (int jj = 0; jj < 8; ++jj) {
            int j16 = jj * 16 + jl;
            float a = __expf(lgv[jj] - m);
            ssum += a;
            float4 v0 = stV[j16], v1 = stV[JT + j16], v2 = stV[2*JT + j16], v3 = stV[3*JT + j16];
            acc[0] += a*v0.x; acc[1] += a*v0.y; acc[2] += a*v0.z; acc[3] += a*v0.w;
            acc[4] += a*v1.x; acc[5] += a*v1.y; acc[6] += a*v1.z; acc[7] += a*v1.w;
            acc[8] += a*v2.x; acc[9] += a*v2.y; acc[10] += a*v2.z; acc[11] += a*v2.w;
            acc[12] += a*v3.x; acc[13] += a*v3.y; acc[14] += a*v3.z; acc[15] += a*v3.w;
            float4 q0 = stVP[j16], q1 = stVP[JT + j16], q2 = stVP[2*JT + j16];
            float4 q3 = stVP[3*JT + j16], q4 = stVP[4*JT + j16], q5 = stVP[5*JT + j16];
            accp[0] += a*q0.x; accp[1] += a*q0.y; accp[2] += a*q0.z; accp[3] += a*q0.w;
            accp[4] += a*q1.x; accp[5] += a*q1.y; accp[6] += a*q1.z; accp[7] += a*q1.w;
            accp[8] += a*q2.x; accp[9] += a*q2.y; accp[10] += a*q2.z; accp[11] += a*q2.w;
            accp[12] += a*q3.x; accp[13] += a*q3.y; accp[14] += a*q3.z; accp[15] += a*q3.w;
            accp[16] += a*q4.x; accp[17] += a*q4.y; accp[18] += a*q4.z; accp[19] += a*q4.w;
            accp[20] += a*q5.x; accp[21] += a*q5.y; accp[22] += a*q5.z; accp[23] += a*q5.w;
        }
        __syncthreads();
    }

    // ---- cross-lane reduce within 16-lane groups ----
    float M = m;
#pragma unroll
    for (int off = 8; off >= 1; off >>= 1) M = fmaxf(M, __shfl_xor(M, off));
    {
        float f = __expf(m - M);
        ssum *= f;
#pragma unroll
        for (int c = 0; c < 16; ++c) acc[c] *= f;
#pragma unroll
        for (int tt = 0; tt < 24; ++tt) accp[tt] *= f;
    }
#pragma unroll
    for (int off = 8; off >= 1; off >>= 1) {
        ssum += __shfl_xor(ssum, off);
#pragma unroll
        for (int c = 0; c < 16; ++c) acc[c] += __shfl_xor(acc[c], off);
#pragma unroll
        for (int tt = 0; tt < 24; ++tt) accp[tt] += __shfl_xor(accp[tt], off);
    }

    // ---- epilogue: STATIC indexing only (rule #20) ----
    const float inv = 1.0f / ssum;
    float* crow = cat + (size_t)bnI * FCAT;

#pragma unroll
    for (int c = 0; c < 16; ++c) {
        if (jl == c) crow[h * 16 + c] = acc[c] * inv;
    }
#pragma unroll
    for (int p = 0; p < 8; ++p) {
        if (jl == p) {
            float g0 = accp[p*3+0] * inv - T[0];
            float g1 = accp[p*3+1] * inv - T[1];
            float g2 = accp[p*3+2] * inv - T[2];
            float lx = R[0]*g0 + R[3]*g1 + R[6]*g2;
            float ly = R[1]*g0 + R[4]*g1 + R[7]*g2;
            float lz = R[2]*g0 + R[5]*g1 + R[8]*g2;
            crow[192 + h*8 + p] = lx;
            crow[288 + h*8 + p] = ly;
            crow[384 + h*8 + p] = lz;
            crow[480 + h*8 + p] = sqrtf(lx*lx + ly*ly + lz*lz + EPSV);
        }
    }
}

// ---------------- Kernel 4: output GEMM ----------------
__global__ __launch_bounds__(384) void out_kernel(
    const float* __restrict__ cat,
    const float* __restrict__ w_out, const float* __restrict__ b_out,
    float* __restrict__ out)
{
    const int row0 = blockIdx.x * 6;
    const int t = threadIdx.x;
    float acc[6] = {0,0,0,0,0,0};
    const float* wp = w_out + t;
    const float* c0 = cat + (size_t)row0 * FCAT;
    for (int d = 0; d < FCAT; d += 4) {
        float4 cv[6];
#pragma unroll
        for (int r = 0; r < 6; ++r)
            cv[r] = *(const float4*)(c0 + (size_t)r * FCAT + d);   // uniform addr
#pragma unroll
        for (int dd = 0; dd < 4; ++dd) {
            float wv = wp[(size_t)(d + dd) * 384];
#pragma unroll
            for (int r = 0; r < 6; ++r) acc[r] += ((const float*)&cv[r])[dd] * wv;
        }
    }
    const float bb = b_out[t];
#pragma unroll
    for (int r = 0; r < 6; ++r) out[(size_t)(row0 + r) * 384 + t] = acc[r] + bb;
}

extern "C" void kernel_launch(void* const* d_in, const int* in_sizes, int n_in,
                              void* d_out, int out_size, void* d_ws, size_t ws_size,
                              hipStream_t stream) {
    const float* s     = (const float*)d_in[0];
    const float* rot   = (const float*)d_in[2];
    const float* trans = (const float*)d_in[3];
    const float* mask  = (const float*)d_in[4];
    const float* w_q   = (const float*)d_in[5];
    const float* b_q   = (const float*)d_in[6];
    const float* w_kv  = (const float*)d_in[7];
    const float* b_kv  = (const float*)d_in[8];
    const float* w_qp  = (const float*)d_in[13];
    const float* b_qp  = (const float*)d_in[14];
    const float* w_kvp = (const float*)d_in[15];
    const float* b_kvp = (const float*)d_in[16];
    const float* hwts  = (const float*)d_in[17];
    const float* w_out = (const float*)d_in[18];
    const float* b_out = (const float*)d_in[19];

    float* ws    = (float*)d_ws;
    float* proj  = ws + WS_PROJ;
    float* Kp    = ws + WS_KP;
    float* Vp    = ws + WS_VP;
    float* KPp   = ws + WS_KPP;
    float* VPp   = ws + WS_VPP;
    float* catb  = ws + WS_CAT;
    float* out   = (float*)d_out;

    hipLaunchKernelGGL(proj_kernel, dim3(384), dim3(384), 0, stream,
                       s, w_q, b_q, w_kv, b_kv, w_qp, b_qp, w_kvp, b_kvp, proj);
    hipLaunchKernelGGL(pack_kernel, dim3(1536), dim3(192), 0, stream,
                       proj, rot, trans, Kp, Vp, KPp, VPp);
    hipLaunchKernelGGL(attn_kernel, dim3(1152), dim3(256), 0, stream,
                       proj, Kp, Vp, KPp, VPp, rot, trans, mask, hwts, catb);
    hipLaunchKernelGGL(out_kernel, dim3(256), dim3(384), 0, stream,
                       catb, w_out, b_out, out);
}

// Round 6
// 112.886 us; speedup vs baseline: 3.0148x; 1.3310x over previous
//
#include <hip/hip_runtime.h>
#include <math.h>

#define Bb 4
#define Nn 384
#define CSs 384
#define Hh 12
#define Cc 16
#define PQq 4
#define PVv 8
#define FPROJ 1152
#define FCAT 576
#define INFV 100000.0f
#define EPSV 1e-8f
#define JT 128

// ws layout (floats)
#define WS_PROJ 0
#define WS_KP   (1536*1152)             // 1,769,472
#define WS_VP   (WS_KP + 48*384*16)     // 2,064,384
#define WS_KPP  (WS_VP + 48*384*16)     // 2,359,296
#define WS_VPP  (WS_KPP + 48*384*12)    // 2,580,480
#define WS_CAT  (WS_VPP + 48*384*24)    // 3,022,848

__device__ __forceinline__ float get_bias(int f,
    const float* __restrict__ b_q, const float* __restrict__ b_kv,
    const float* __restrict__ b_qp, const float* __restrict__ b_kvp)
{
    if (f < 192) return b_q[f];
    if (f < 576) return b_kv[f - 192];
    if (f < 720) return b_qp[f - 576];
    return b_kvp[f - 720];
}

// ---------------- Kernel 1: projection GEMM, LDS-tiled ----------------
// C[1536][1152] = s[1536][384] @ W[384][1152] + bias
// grid 432 = 24 row-tiles x 18 col-tiles; 256 threads; 4x4 outputs/thread
__global__ __launch_bounds__(256) void proj_kernel(
    const float* __restrict__ s,
    const float* __restrict__ w_q, const float* __restrict__ b_q,
    const float* __restrict__ w_kv, const float* __restrict__ b_kv,
    const float* __restrict__ w_qp, const float* __restrict__ b_qp,
    const float* __restrict__ w_kvp, const float* __restrict__ b_kvp,
    float* __restrict__ proj)
{
    __shared__ float sT[16 * 68];   // [k][m], padded stride 68
    __shared__ float wT[16 * 64];   // [k][f]

    const int bm = blockIdx.x % 24;
    const int bn = blockIdx.x / 24;
    const int m0 = bm * 64;
    const int f0 = bn * 64;
    const int t = threadIdx.x;

    // staging roles
    const int smm = t >> 2;          // 0..63
    const int skq = t & 3;           // 0..3 (f4 of k)
    const int wkk = t >> 4;          // 0..15
    const int wfq = t & 15;          // 0..15 (f4 of f)

    // weight source select (per thread, constant over k)
    const float* wb; int ldw; int colof;
    {
        int f = f0 + wfq * 4;
        if (f < 192)      { wb = w_q;   ldw = 192; colof = f; }
        else if (f < 576) { wb = w_kv;  ldw = 384; colof = f - 192; }
        else if (f < 720) { wb = w_qp;  ldw = 144; colof = f - 576; }
        else              { wb = w_kvp; ldw = 432; colof = f - 720; }
    }
    const float* wptr = wb + (size_t)wkk * ldw + colof;
    const float* sptr = s + (size_t)(m0 + smm) * CSs + skq * 4;

    // compute roles
    const int tm = t >> 4;           // 0..15 (row quad)
    const int tn = t & 15;           // 0..15 (col quad)

    float acc[16];
#pragma unroll
    for (int e = 0; e < 16; ++e) acc[e] = 0.0f;

    float4 sreg = *(const float4*)sptr;
    float4 wreg = *(const float4*)wptr;

    for (int ks = 0; ks < 24; ++ks) {
        // write staged regs to LDS
        sT[(skq * 4 + 0) * 68 + smm] = sreg.x;
        sT[(skq * 4 + 1) * 68 + smm] = sreg.y;
        sT[(skq * 4 + 2) * 68 + smm] = sreg.z;
        sT[(skq * 4 + 3) * 68 + smm] = sreg.w;
        *(float4*)&wT[wkk * 64 + wfq * 4] = wreg;
        __syncthreads();

        // prefetch next tile
        if (ks + 1 < 24) {
            sreg = *(const float4*)(sptr + (ks + 1) * 16);
            wreg = *(const float4*)(wptr + (size_t)(ks + 1) * 16 * ldw);
        }

        // compute 16 k-slices
#pragma unroll
        for (int kk = 0; kk < 16; ++kk) {
            float4 a = *(const float4*)&sT[kk * 68 + tm * 4];
            float4 b = *(const float4*)&wT[kk * 64 + tn * 4];
            acc[0]  += a.x * b.x; acc[1]  += a.x * b.y; acc[2]  += a.x * b.z; acc[3]  += a.x * b.w;
            acc[4]  += a.y * b.x; acc[5]  += a.y * b.y; acc[6]  += a.y * b.z; acc[7]  += a.y * b.w;
            acc[8]  += a.z * b.x; acc[9]  += a.z * b.y; acc[10] += a.z * b.z; acc[11] += a.z * b.w;
            acc[12] += a.w * b.x; acc[13] += a.w * b.y; acc[14] += a.w * b.z; acc[15] += a.w * b.w;
        }
        __syncthreads();
    }

    // epilogue
    float bias[4];
#pragma unroll
    for (int cc = 0; cc < 4; ++cc)
        bias[cc] = get_bias(f0 + tn * 4 + cc, b_q, b_kv, b_qp, b_kvp);
#pragma unroll
    for (int rr = 0; rr < 4; ++rr) {
        float4 o;
        o.x = acc[rr * 4 + 0] + bias[0];
        o.y = acc[rr * 4 + 1] + bias[1];
        o.z = acc[rr * 4 + 2] + bias[2];
        o.w = acc[rr * 4 + 3] + bias[3];
        *(float4*)&proj[(size_t)(m0 + tm * 4 + rr) * FPROJ + f0 + tn * 4] = o;
    }
}

// ---------------- Kernel 2: rigid-apply + pack ----------------
__global__ __launch_bounds__(192) void pack_kernel(
    const float* __restrict__ proj,
    const float* __restrict__ rot, const float* __restrict__ trans,
    float* __restrict__ Kp, float* __restrict__ Vp,
    float* __restrict__ KPp, float* __restrict__ VPp)
{
    const int bn = blockIdx.x;
    const int b = bn / Nn;
    const int n = bn % Nn;
    const int t = threadIdx.x;
    const float* R = rot + (size_t)bn * 9;
    const float* T = trans + (size_t)bn * 3;
    const float* pr = proj + (size_t)bn * FPROJ;

    if (t < 144) {
        float x = pr[720 + t];
        float y = pr[720 + 144 + t];
        float z = pr[720 + 288 + t];
        float ox = R[0]*x + R[1]*y + R[2]*z + T[0];
        float oy = R[3]*x + R[4]*y + R[5]*z + T[1];
        float oz = R[6]*x + R[7]*y + R[8]*z + T[2];
        int h = t / 12, pp = t % 12;
        int bh = b * Hh + h;
        if (pp < PQq) {
            float* o = KPp + ((size_t)(bh * Nn + n)) * 12 + pp * 3;
            o[0] = ox; o[1] = oy; o[2] = oz;
        } else {
            float* o = VPp + ((size_t)(bh * Nn + n)) * 24 + (pp - PQq) * 3;
            o[0] = ox; o[1] = oy; o[2] = oz;
        }
    }
#pragma unroll
    for (int rep = 0; rep < 2; ++rep) {
        int idx = t + rep * 192;
        int h = idx / 32, c2 = idx % 32;
        int bh = b * Hh + h;
        float v = pr[192 + h * 32 + c2];
        if (c2 < 16) Kp[((size_t)(bh * Nn + n)) * 16 + c2] = v;
        else         Vp[((size_t)(bh * Nn + n)) * 16 + (c2 - 16)] = v;
    }
}

// ---------------- Kernel 3: attention v5 (unchanged from r5) ----------------
__global__ __launch_bounds__(256, 3) void attn_kernel(
    const float* __restrict__ proj,
    const float* __restrict__ Kp, const float* __restrict__ Vp,
    const float* __restrict__ KPp, const float* __restrict__ VPp,
    const float* __restrict__ rot, const float* __restrict__ trans,
    const float* __restrict__ mask, const float* __restrict__ head_weights,
    float* __restrict__ cat)
{
    __shared__ float4 stK[4*JT];
    __shared__ float4 stKP[3*JT];
    __shared__ float4 stV[4*JT];
    __shared__ float4 stVP[6*JT];
    __shared__ float  stM[Nn];

    const int bid = blockIdx.x;
    const int ib = bid % 24;
    const int h  = (bid / 24) % Hh;
    const int b  = bid / (24 * Hh);
    const int tid = threadIdx.x;
    const int w = tid >> 6;
    const int lane = tid & 63;
    const int rg = lane >> 4;
    const int jl = lane & 15;
    const int i = ib * 16 + w * 4 + rg;
    const int bnI = b * Nn + i;
    const int bh = b * Hh + h;

    for (int e = tid; e < Nn; e += 256) stM[e] = mask[b * Nn + e];

    const float* qrow = proj + (size_t)bnI * FPROJ + h * Cc;
    float qv[16];
#pragma unroll
    for (int c = 0; c < 16; ++c) qv[c] = qrow[c];

    const float* R = rot + (size_t)bnI * 9;
    const float* T = trans + (size_t)bnI * 3;
    float qpv[12];
    {
        const float* pq = proj + (size_t)bnI * FPROJ + 576;
#pragma unroll
        for (int p = 0; p < PQq; ++p) {
            float x = pq[h * PQq + p];
            float y = pq[48 + h * PQq + p];
            float z = pq[96 + h * PQq + p];
            qpv[p*3+0] = R[0]*x + R[1]*y + R[2]*z + T[0];
            qpv[p*3+1] = R[3]*x + R[4]*y + R[5]*z + T[1];
            qpv[p*3+2] = R[6]*x + R[7]*y + R[8]*z + T[2];
        }
    }

    const float hw = log1pf(expf(head_weights[h]));
    const float wc = -0.5f * hw * 0.13608276348795434f;
    const float scale2 = 2.0f * 0.14433756729740643f;
    const float mi = mask[bnI];

    const float* KpB  = Kp  + (size_t)(bh * Nn) * 16;
    const float* VpB  = Vp  + (size_t)(bh * Nn) * 16;
    const float* KPpB = KPp + (size_t)(bh * Nn) * 12;
    const float* VPpB = VPp + (size_t)(bh * Nn) * 24;

    float m = -3.0e38f, ssum = 0.0f;
    float acc[16]; float accp[24];
#pragma unroll
    for (int c = 0; c < 16; ++c) acc[c] = 0.0f;
#pragma unroll
    for (int tt = 0; tt < 24; ++tt) accp[tt] = 0.0f;

    for (int tile = 0; tile < Nn / JT; ++tile) {
        const int jb = tile * JT;
#pragma unroll
        for (int k = 0; k < 2; ++k) {
            int e = tid + k * 256;
            int j = e >> 2, c4 = e & 3;
            stK[c4 * JT + j] = *(const float4*)(KpB + ((size_t)(jb + j)) * 16 + c4 * 4);
            stV[c4 * JT + j] = *(const float4*)(VpB + ((size_t)(jb + j)) * 16 + c4 * 4);
        }
        {
            int cp = tid >> 7, j = tid & 127;
            stKP[cp * JT + j] = *(const float4*)(KPpB + ((size_t)(jb + j)) * 12 + cp * 4);
        }
        if (tid < 128) {
            stKP[2 * JT + tid] = *(const float4*)(KPpB + ((size_t)(jb + tid)) * 12 + 8);
        }
#pragma unroll
        for (int k = 0; k < 3; ++k) {
            int e = tid + k * 256;
            int cp = e >> 7, j = e & 127;
            stVP[cp * JT + j] = *(const float4*)(VPpB + ((size_t)(jb + j)) * 24 + cp * 4);
        }
        __syncthreads();

        float lgv[8];
        float tmax = -3.0e38f;
#pragma unroll
        for (int jj = 0; jj < 8; ++jj) {
            int j16 = jj * 16 + jl;
            float4 k0 = stK[j16], k1 = stK[JT + j16], k2 = stK[2*JT + j16], k3 = stK[3*JT + j16];
            float dot = qv[0]*k0.x + qv[1]*k0.y + qv[2]*k0.z + qv[3]*k0.w
                      + qv[4]*k1.x + qv[5]*k1.y + qv[6]*k1.z + qv[7]*k1.w
                      + qv[8]*k2.x + qv[9]*k2.y + qv[10]*k2.z + qv[11]*k2.w
                      + qv[12]*k3.x + qv[13]*k3.y + qv[14]*k3.z + qv[15]*k3.w;
            float4 p0 = stKP[j16], p1 = stKP[JT + j16], p2 = stKP[2*JT + j16];
            float d0 = qpv[0]-p0.x, d1 = qpv[1]-p0.y, d2 = qpv[2]-p0.z, d3 = qpv[3]-p0.w;
            float d4 = qpv[4]-p1.x, d5 = qpv[5]-p1.y, d6 = qpv[6]-p1.z, d7 = qpv[7]-p1.w;
            float d8 = qpv[8]-p2.x, d9 = qpv[9]-p2.y, d10 = qpv[10]-p2.z, d11 = qpv[11]-p2.w;
            float sq = d0*d0 + d1*d1 + d2*d2 + d3*d3 + d4*d4 + d5*d5
                     + d6*d6 + d7*d7 + d8*d8 + d9*d9 + d10*d10 + d11*d11;
            float lgt = scale2 * dot + wc * sq + INFV * (mi * stM[jb + j16] - 1.0f);
            lgv[jj] = lgt;
            tmax = fmaxf(tmax, lgt);
        }

        if (__any(tmax > m)) {
            float mnew = fmaxf(m, tmax);
            float f = __expf(m - mnew);
            m = mnew;
            ssum *= f;
#pragma unroll
            for (int c = 0; c < 16; ++c) acc[c] *= f;
#pragma unroll
            for (int tt = 0; tt < 24; ++tt) accp[tt] *= f;
        }

#pragma unroll
        for (int jj = 0; jj < 8; ++jj) {
            int j16 = jj * 16 + jl;
            float a = __expf(lgv[jj] - m);
            ssum += a;
            float4 v0 = stV[j16], v1 = stV[JT + j16], v2 = stV[2*JT + j16], v3 = stV[3*JT + j16];
            acc[0] += a*v0.x; acc[1] += a*v0.y; acc[2] += a*v0.z; acc[3] += a*v0.w;
            acc[4] += a*v1.x; acc[5] += a*v1.y; acc[6] += a*v1.z; acc[7] += a*v1.w;
            acc[8] += a*v2.x; acc[9] += a*v2.y; acc[10] += a*v2.z; acc[11] += a*v2.w;
            acc[12] += a*v3.x; acc[13] += a*v3.y; acc[14] += a*v3.z; acc[15] += a*v3.w;
            float4 q0 = stVP[j16], q1 = stVP[JT + j16], q2 = stVP[2*JT + j16];
            float4 q3 = stVP[3*JT + j16], q4 = stVP[4*JT + j16], q5 = stVP[5*JT + j16];
            accp[0] += a*q0.x; accp[1] += a*q0.y; accp[2] += a*q0.z; accp[3] += a*q0.w;
            accp[4] += a*q1.x; accp[5] += a*q1.y; accp[6] += a*q1.z; accp[7] += a*q1.w;
            accp[8] += a*q2.x; accp[9] += a*q2.y; accp[10] += a*q2.z; accp[11] += a*q2.w;
            accp[12] += a*q3.x; accp[13] += a*q3.y; accp[14] += a*q3.z; accp[15] += a*q3.w;
            accp[16] += a*q4.x; accp[17] += a*q4.y; accp[18] += a*q4.z; accp[19] += a*q4.w;
            accp[20] += a*q5.x; accp[21] += a*q5.y; accp[22] += a*q5.z; accp[23] += a*q5.w;
        }
        __syncthreads();
    }

    float M = m;
#pragma unroll
    for (int off = 8; off >= 1; off >>= 1) M = fmaxf(M, __shfl_xor(M, off));
    {
        float f = __expf(m - M);
        ssum *= f;
#pragma unroll
        for (int c = 0; c < 16; ++c) acc[c] *= f;
#pragma unroll
        for (int tt = 0; tt < 24; ++tt) accp[tt] *= f;
    }
#pragma unroll
    for (int off = 8; off >= 1; off >>= 1) {
        ssum += __shfl_xor(ssum, off);
#pragma unroll
        for (int c = 0; c < 16; ++c) acc[c] += __shfl_xor(acc[c], off);
#pragma unroll
        for (int tt = 0; tt < 24; ++tt) accp[tt] += __shfl_xor(accp[tt], off);
    }

    const float inv = 1.0f / ssum;
    float* crow = cat + (size_t)bnI * FCAT;

#pragma unroll
    for (int c = 0; c < 16; ++c) {
        if (jl == c) crow[h * 16 + c] = acc[c] * inv;
    }
#pragma unroll
    for (int p = 0; p < 8; ++p) {
        if (jl == p) {
            float g0 = accp[p*3+0] * inv - T[0];
            float g1 = accp[p*3+1] * inv - T[1];
            float g2 = accp[p*3+2] * inv - T[2];
            float lx = R[0]*g0 + R[3]*g1 + R[6]*g2;
            float ly = R[1]*g0 + R[4]*g1 + R[7]*g2;
            float lz = R[2]*g0 + R[5]*g1 + R[8]*g2;
            crow[192 + h*8 + p] = lx;
            crow[288 + h*8 + p] = ly;
            crow[384 + h*8 + p] = lz;
            crow[480 + h*8 + p] = sqrtf(lx*lx + ly*ly + lz*lz + EPSV);
        }
    }
}

// ---------------- Kernel 4: output GEMM, LDS-tiled ----------------
// out[1536][384] = cat[1536][576] @ w_out[576][384] + b_out
// grid 144 = 24 row-tiles x 6 col-tiles; 256 threads; 4x4/thread
__global__ __launch_bounds__(256) void out_kernel(
    const float* __restrict__ cat,
    const float* __restrict__ w_out, const float* __restrict__ b_out,
    float* __restrict__ out)
{
    __shared__ float cT[16 * 68];   // [k][m]
    __shared__ float wT[16 * 64];   // [k][n]

    const int bm = blockIdx.x % 24;
    const int bn = blockIdx.x / 24;
    const int m0 = bm * 64;
    const int n0 = bn * 64;
    const int t = threadIdx.x;

    const int smm = t >> 2;
    const int skq = t & 3;
    const int wkk = t >> 4;
    const int wfq = t & 15;

    const float* cptr = cat + (size_t)(m0 + smm) * FCAT + skq * 4;
    const float* wptr = w_out + (size_t)wkk * 384 + n0 + wfq * 4;

    const int tm = t >> 4;
    const int tn = t & 15;

    float acc[16];
#pragma unroll
    for (int e = 0; e < 16; ++e) acc[e] = 0.0f;

    float4 creg = *(const float4*)cptr;
    float4 wreg = *(const float4*)wptr;

    for (int ks = 0; ks < 36; ++ks) {
        cT[(skq * 4 + 0) * 68 + smm] = creg.x;
        cT[(skq * 4 + 1) * 68 + smm] = creg.y;
        cT[(skq * 4 + 2) * 68 + smm] = creg.z;
        cT[(skq * 4 + 3) * 68 + smm] = creg.w;
        *(float4*)&wT[wkk * 64 + wfq * 4] = wreg;
        __syncthreads();

        if (ks + 1 < 36) {
            creg = *(const float4*)(cptr + (ks + 1) * 16);
            wreg = *(const float4*)(wptr + (size_t)(ks + 1) * 16 * 384);
        }

#pragma unroll
        for (int kk = 0; kk < 16; ++kk) {
            float4 a = *(const float4*)&cT[kk * 68 + tm * 4];
            float4 b = *(const float4*)&wT[kk * 64 + tn * 4];
            acc[0]  += a.x * b.x; acc[1]  += a.x * b.y; acc[2]  += a.x * b.z; acc[3]  += a.x * b.w;
            acc[4]  += a.y * b.x; acc[5]  += a.y * b.y; acc[6]  += a.y * b.z; acc[7]  += a.y * b.w;
            acc[8]  += a.z * b.x; acc[9]  += a.z * b.y; acc[10] += a.z * b.z; acc[11] += a.z * b.w;
            acc[12] += a.w * b.x; acc[13] += a.w * b.y; acc[14] += a.w * b.z; acc[15] += a.w * b.w;
        }
        __syncthreads();
    }

    float4 bias = *(const float4*)&b_out[n0 + tn * 4];
#pragma unroll
    for (int rr = 0; rr < 4; ++rr) {
        float4 o;
        o.x = acc[rr * 4 + 0] + bias.x;
        o.y = acc[rr * 4 + 1] + bias.y;
        o.z = acc[rr * 4 + 2] + bias.z;
        o.w = acc[rr * 4 + 3] + bias.w;
        *(float4*)&out[(size_t)(m0 + tm * 4 + rr) * 384 + n0 + tn * 4] = o;
    }
}

extern "C" void kernel_launch(void* const* d_in, const int* in_sizes, int n_in,
                              void* d_out, int out_size, void* d_ws, size_t ws_size,
                              hipStream_t stream) {
    const float* s     = (const float*)d_in[0];
    const float* rot   = (const float*)d_in[2];
    const float* trans = (const float*)d_in[3];
    const float* mask  = (const float*)d_in[4];
    const float* w_q   = (const float*)d_in[5];
    const float* b_q   = (const float*)d_in[6];
    const float* w_kv  = (const float*)d_in[7];
    const float* b_kv  = (const float*)d_in[8];
    const float* w_qp  = (const float*)d_in[13];
    const float* b_qp  = (const float*)d_in[14];
    const float* w_kvp = (const float*)d_in[15];
    const float* b_kvp = (const float*)d_in[16];
    const float* hwts  = (const float*)d_in[17];
    const float* w_out = (const float*)d_in[18];
    const float* b_out = (const float*)d_in[19];

    float* ws    = (float*)d_ws;
    float* proj  = ws + WS_PROJ;
    float* Kp    = ws + WS_KP;
    float* Vp    = ws + WS_VP;
    float* KPp   = ws + WS_KPP;
    float* VPp   = ws + WS_VPP;
    float* catb  = ws + WS_CAT;
    float* out   = (float*)d_out;

    hipLaunchKernelGGL(proj_kernel, dim3(432), dim3(256), 0, stream,
                       s, w_q, b_q, w_kv, b_kv, w_qp, b_qp, w_kvp, b_kvp, proj);
    hipLaunchKernelGGL(pack_kernel, dim3(1536), dim3(192), 0, stream,
                       proj, rot, trans, Kp, Vp, KPp, VPp);
    hipLaunchKernelGGL(attn_kernel, dim3(1152), dim3(256), 0, stream,
                       proj, Kp, Vp, KPp, VPp, rot, trans, mask, hwts, catb);
    hipLaunchKernelGGL(out_kernel, dim3(144), dim3(256), 0, stream,
                       catb, w_out, b_out, out);
}